// Round 1
// baseline (217.922 us; speedup 1.0000x reference)
//
#include <hip/hip_runtime.h>
#include <hip/hip_bf16.h>

// Problem constants (reference: H=W=64, C=2048, IMG=224)
#define HW    4096          // H*W rows
#define CDIM  2048          // channels (K)
#define IMG   224

typedef short short8 __attribute__((ext_vector_type(8)));   // 8 bf16 in 4 VGPRs
typedef float f32x4  __attribute__((ext_vector_type(4)));

// ---------------------------------------------------------------------------
// async global->LDS, 16B per lane. Dest = wave-uniform base + lane*16.
__device__ __forceinline__ void gload_lds16(const void* g, void* l) {
    __builtin_amdgcn_global_load_lds(
        (const __attribute__((address_space(1))) unsigned int*)g,
        (__attribute__((address_space(3))) unsigned int*)l,
        16, 0, 0);
}

// ---------------------------------------------------------------------------
// Kernel 1: convert fp32 -> bf16 copies, and accumulate column sums.
// grid (8 colgroups, 32 rowgroups, 2 matrices), block 256.
__global__ __launch_bounds__(256) void convert_colsum_kernel(
    const float* __restrict__ feat,
    __hip_bfloat16* __restrict__ Ab, __hip_bfloat16* __restrict__ Bb,
    float* __restrict__ s0, float* __restrict__ s1) {
    int c = blockIdx.x * 256 + threadIdx.x;      // column 0..2047
    int m = blockIdx.z;
    const float* src = feat + (size_t)m * HW * CDIM;
    __hip_bfloat16* dst = m ? Bb : Ab;
    float* s = m ? s1 : s0;
    int r0 = blockIdx.y * 128;
    float acc = 0.f;
    for (int r = r0; r < r0 + 128; ++r) {
        float v = src[(size_t)r * CDIM + c];
        acc += v;
        dst[(size_t)r * CDIM + c] = __float2bfloat16(v);
    }
    atomicAdd(&s[c], acc);
}

// ---------------------------------------------------------------------------
// Kernel 2: GEMM-max. C = A * B^T over bf16 copies; only per-block max kept.
// 128x128 tile per block, BK=32, 4 waves each computing 64x64 via 4x4 grid of
// 16x16x32 MFMAs. grid (32,32), block 256.
__global__ __launch_bounds__(256) void gemm_max_kernel(
    const __hip_bfloat16* __restrict__ Abh,
    const __hip_bfloat16* __restrict__ Bbh,
    float* __restrict__ blockmax) {
    __shared__ short As[128 * 32];
    __shared__ short Bs[128 * 32];
    __shared__ float wred[4];

    const int tid  = threadIdx.x;
    const int lane = tid & 63;
    const int wave = tid >> 6;
    const int bm = blockIdx.y, bn = blockIdx.x;
    const int wm = wave >> 1, wn = wave & 1;

    f32x4 acc[4][4];
#pragma unroll
    for (int i = 0; i < 4; ++i)
#pragma unroll
        for (int j = 0; j < 4; ++j)
            acc[i][j] = (f32x4){0.f, 0.f, 0.f, 0.f};

    // staging: thread covers 8 bf16 at (row=tid/4, col=(tid%4)*8) and +64 rows
    const int sr = tid >> 2;
    const int sc = (tid & 3) * 8;
    const short* gA = (const short*)Abh + (size_t)(bm * 128 + sr) * CDIM + sc;
    const short* gB = (const short*)Bbh + (size_t)(bn * 128 + sr) * CDIM + sc;
    short* lA = &As[sr * 32 + sc];
    short* lB = &Bs[sr * 32 + sc];

    const int fr = lane & 15;        // fragment row (m or n)
    const int kc = (lane >> 4) * 8;  // k-chunk within BK

    for (int k0 = 0; k0 < CDIM; k0 += 32) {
        gload_lds16(gA + k0, lA);
        gload_lds16(gA + k0 + (size_t)64 * CDIM, lA + 64 * 32);
        gload_lds16(gB + k0, lB);
        gload_lds16(gB + k0 + (size_t)64 * CDIM, lB + 64 * 32);
        __syncthreads();

        short8 af[4], bf[4];
#pragma unroll
        for (int mt = 0; mt < 4; ++mt)
            af[mt] = *(const short8*)&As[(wm * 64 + mt * 16 + fr) * 32 + kc];
#pragma unroll
        for (int nt = 0; nt < 4; ++nt)
            bf[nt] = *(const short8*)&Bs[(wn * 64 + nt * 16 + fr) * 32 + kc];
#pragma unroll
        for (int mt = 0; mt < 4; ++mt)
#pragma unroll
            for (int nt = 0; nt < 4; ++nt)
                acc[mt][nt] = __builtin_amdgcn_mfma_f32_16x16x32_bf16(
                    af[mt], bf[nt], acc[mt][nt], 0, 0, 0);
        __syncthreads();
    }

    // per-lane max over all 256 accumulated values (layout-agnostic)
    float m = -3.4e38f;
#pragma unroll
    for (int mt = 0; mt < 4; ++mt)
#pragma unroll
        for (int nt = 0; nt < 4; ++nt)
#pragma unroll
            for (int i = 0; i < 4; ++i)
                m = fmaxf(m, acc[mt][nt][i]);
#pragma unroll
    for (int off = 32; off; off >>= 1)
        m = fmaxf(m, __shfl_down(m, off));
    if (lane == 0) wred[wave] = m;
    __syncthreads();
    if (tid == 0)
        blockmax[blockIdx.y * gridDim.x + blockIdx.x] =
            fmaxf(fmaxf(wred[0], wred[1]), fmaxf(wred[2], wred[3]));
}

// ---------------------------------------------------------------------------
// Kernel 3: reduce 1024 block maxes to one float.
__global__ __launch_bounds__(256) void reduce_max_kernel(
    const float* __restrict__ bmax, float* __restrict__ Mout) {
    int tid = threadIdx.x;
    float m = -3.4e38f;
    for (int i = tid; i < 1024; i += 256) m = fmaxf(m, bmax[i]);
#pragma unroll
    for (int off = 32; off; off >>= 1) m = fmaxf(m, __shfl_down(m, off));
    __shared__ float w[4];
    if ((tid & 63) == 0) w[tid >> 6] = m;
    __syncthreads();
    if (tid == 0)
        *Mout = fmaxf(fmaxf(w[0], w[1]), fmaxf(w[2], w[3]));
}

// ---------------------------------------------------------------------------
// Kernel 4: saliency matvecs in fp32.
// sal[0..4095]   = (x0 row r) . s1 / M      (decom_1)
// sal[4096..]    = (x1 row r) . s0 / M      (decom_2)
// one wave per row; grid 2048 blocks x 256 threads (4 rows/block).
__global__ __launch_bounds__(256) void saliency_kernel(
    const float* __restrict__ feat, const float* __restrict__ s0,
    const float* __restrict__ s1, const float* __restrict__ Mval,
    float* __restrict__ sal) {
    int tid = threadIdx.x, lane = tid & 63, wave = tid >> 6;
    int g = blockIdx.x * 4 + wave;           // 0..8191
    const float* x;
    const float* s;
    if (g < HW) { x = feat + (size_t)g * CDIM;                      s = s1; }
    else        { x = feat + (size_t)HW * CDIM + (size_t)(g - HW) * CDIM; s = s0; }
    float acc = 0.f;
    for (int c = lane; c < CDIM; c += 64) acc += x[c] * s[c];
#pragma unroll
    for (int off = 32; off; off >>= 1) acc += __shfl_down(acc, off);
    if (lane == 0) sal[g] = acc / (*Mval);
}

// ---------------------------------------------------------------------------
// Kernel 5: half-pixel bilinear resize [2,64,64] -> [2,224,224].
__global__ __launch_bounds__(256) void resize_kernel(
    const float* __restrict__ sal, float* __restrict__ out) {
    int idx = blockIdx.x * 256 + threadIdx.x;
    if (idx >= 2 * IMG * IMG) return;
    int ch = idx / (IMG * IMG);
    int rem = idx % (IMG * IMG);
    int oy = rem / IMG, ox = rem % IMG;
    const float scale = 64.0f / (float)IMG;
    float sy = ((float)oy + 0.5f) * scale - 0.5f;
    float sx = ((float)ox + 0.5f) * scale - 0.5f;
    float fy0 = floorf(sy), fx0 = floorf(sx);
    float wy = sy - fy0, wx = sx - fx0;
    int y0 = (int)fy0, x0 = (int)fx0;
    int y1 = min(max(y0 + 1, 0), 63), x1 = min(max(x0 + 1, 0), 63);
    y0 = min(max(y0, 0), 63); x0 = min(max(x0, 0), 63);
    const float* p = sal + ch * HW;
    float v00 = p[y0 * 64 + x0], v01 = p[y0 * 64 + x1];
    float v10 = p[y1 * 64 + x0], v11 = p[y1 * 64 + x1];
    out[idx] = (1.f - wy) * ((1.f - wx) * v00 + wx * v01) +
               wy * ((1.f - wx) * v10 + wx * v11);
}

// ---------------------------------------------------------------------------
extern "C" void kernel_launch(void* const* d_in, const int* in_sizes, int n_in,
                              void* d_out, int out_size, void* d_ws, size_t ws_size,
                              hipStream_t stream) {
    const float* feat = (const float*)d_in[0];   // [2,64,64,2048] fp32
    float* out = (float*)d_out;                  // [2,224,224] fp32

    // workspace layout
    char* ws = (char*)d_ws;
    __hip_bfloat16* Ab = (__hip_bfloat16*)ws;                       // 16 MB
    __hip_bfloat16* Bb = (__hip_bfloat16*)(ws + (size_t)16 * 1024 * 1024);
    float* s0   = (float*)(ws + (size_t)32 * 1024 * 1024);          // 2048
    float* s1   = s0 + CDIM;                                        // 2048
    float* bmax = s1 + CDIM;                                        // 1024
    float* Mval = bmax + 1024;                                      // 1
    float* sal  = Mval + 1;                                         // 8192

    // zero the column-sum accumulators (ws is poisoned 0xAA each launch)
    hipMemsetAsync(s0, 0, 2 * CDIM * sizeof(float), stream);

    convert_colsum_kernel<<<dim3(8, 32, 2), 256, 0, stream>>>(feat, Ab, Bb, s0, s1);
    gemm_max_kernel<<<dim3(32, 32), 256, 0, stream>>>(Ab, Bb, bmax);
    reduce_max_kernel<<<1, 256, 0, stream>>>(bmax, Mval);
    saliency_kernel<<<2048, 256, 0, stream>>>(feat, s0, s1, Mval, sal);
    int nout = 2 * IMG * IMG;
    resize_kernel<<<(nout + 255) / 256, 256, 0, stream>>>(sal, out);
}

// Round 2
// 201.384 us; speedup vs baseline: 1.0821x; 1.0821x over previous
//
#include <hip/hip_runtime.h>
#include <hip/hip_bf16.h>

// Problem constants (reference: H=W=64, C=2048, IMG=224)
#define HW    4096          // H*W rows
#define CDIM  2048          // channels (K)
#define IMG   224

typedef short short4v __attribute__((ext_vector_type(4)));
typedef short short8  __attribute__((ext_vector_type(8)));   // 8 bf16 in 4 VGPRs
typedef float f32x4   __attribute__((ext_vector_type(4)));

__device__ __forceinline__ float bf16s_to_f32(short s) {
    unsigned u = ((unsigned)(unsigned short)s) << 16;
    return __builtin_bit_cast(float, u);
}
__device__ __forceinline__ short f32_to_bf16s(float f) {
    return __builtin_bit_cast(short, __float2bfloat16(f));
}

// async global->LDS, 16B per lane. Dest must be wave-uniform base + lane*16.
__device__ __forceinline__ void gload_lds16(const void* g, void* l) {
    __builtin_amdgcn_global_load_lds(
        (const __attribute__((address_space(1))) unsigned int*)g,
        (__attribute__((address_space(3))) unsigned int*)l,
        16, 0, 0);
}

// ---------------------------------------------------------------------------
// Kernel 1: convert fp32 -> bf16 copies + column sums.
// float4 loads, short4 bf16 stores. grid (2, 128, 2), block 256.
__global__ __launch_bounds__(256) void convert_colsum_kernel(
    const float* __restrict__ feat,
    short* __restrict__ Ab, short* __restrict__ Bb,
    float* __restrict__ s0, float* __restrict__ s1) {
    const int tid = threadIdx.x;
    const int c0 = (blockIdx.x * 256 + tid) * 4;     // column group of 4
    const int m = blockIdx.z;
    const float* src = feat + (size_t)m * HW * CDIM;
    short* dst = m ? Bb : Ab;
    float* s = m ? s1 : s0;
    const int r0 = blockIdx.y * 32;
    float a0 = 0.f, a1 = 0.f, a2 = 0.f, a3 = 0.f;
    for (int r = r0; r < r0 + 32; ++r) {
        float4 v = *(const float4*)&src[(size_t)r * CDIM + c0];
        a0 += v.x; a1 += v.y; a2 += v.z; a3 += v.w;
        short4v o;
        o[0] = f32_to_bf16s(v.x); o[1] = f32_to_bf16s(v.y);
        o[2] = f32_to_bf16s(v.z); o[3] = f32_to_bf16s(v.w);
        *(short4v*)&dst[(size_t)r * CDIM + c0] = o;
    }
    atomicAdd(&s[c0 + 0], a0);
    atomicAdd(&s[c0 + 1], a1);
    atomicAdd(&s[c0 + 2], a2);
    atomicAdd(&s[c0 + 3], a3);
}

// ---------------------------------------------------------------------------
// Kernel 2: GEMM-max with XOR-swizzled LDS chunk layout.
// C = A * B^T over bf16; only per-block max kept. 128x128 tile, BK=32,
// 4 waves x (4x4 grid of 16x16x32 MFMAs). grid (32,32), block 256.
//
// Swizzle: logical k-chunk c of row r lives at physical chunk position
// p = c ^ ((r>>1)&3). Staging keeps LDS dest = lane*16 (required by
// global_load_lds) and instead permutes the GLOBAL source chunk; fragment
// reads apply the same XOR. Makes every aligned 8-lane ds_read_b128 beat
// cover all 8 16B bank-groups (was 2 -> 4-way conflicts).
__global__ __launch_bounds__(256) void gemm_max_kernel(
    const short* __restrict__ Abh,
    const short* __restrict__ Bbh,
    float* __restrict__ blockmax) {
    __shared__ short As[128 * 32];
    __shared__ short Bs[128 * 32];
    __shared__ float wred[4];

    const int tid  = threadIdx.x;
    const int lane = tid & 63;
    const int wave = tid >> 6;
    const int bm = blockIdx.y, bn = blockIdx.x;
    const int wm = wave >> 1, wn = wave & 1;

    f32x4 acc[4][4];
#pragma unroll
    for (int i = 0; i < 4; ++i)
#pragma unroll
        for (int j = 0; j < 4; ++j)
            acc[i][j] = (f32x4){0.f, 0.f, 0.f, 0.f};

    // staging: lane covers LDS chunk (sr, pc); fetches global chunk gc = pc^sw
    const int sr = tid >> 2;                 // 0..63 (row within half-tile)
    const int pc = tid & 3;                  // physical chunk position
    const int gc = pc ^ ((sr >> 1) & 3);     // swizzled logical chunk
    const short* gA = Abh + (size_t)(bm * 128 + sr) * CDIM + gc * 8;
    const short* gB = Bbh + (size_t)(bn * 128 + sr) * CDIM + gc * 8;
    short* lA = &As[sr * 32 + pc * 8];       // == lds_base + tid*16 bytes
    short* lB = &Bs[sr * 32 + pc * 8];

    // fragment read: logical chunk cc of row fr is at physical cc^((fr>>1)&3)
    const int fr = lane & 15;
    const int cc = lane >> 4;
    const int pk = (cc ^ ((fr >> 1) & 3)) * 8;

    for (int k0 = 0; k0 < CDIM; k0 += 32) {
        gload_lds16(gA + k0, lA);
        gload_lds16(gA + k0 + (size_t)64 * CDIM, lA + 64 * 32);
        gload_lds16(gB + k0, lB);
        gload_lds16(gB + k0 + (size_t)64 * CDIM, lB + 64 * 32);
        __syncthreads();

        short8 af[4], bf[4];
#pragma unroll
        for (int mt = 0; mt < 4; ++mt)
            af[mt] = *(const short8*)&As[(wm * 64 + mt * 16 + fr) * 32 + pk];
#pragma unroll
        for (int nt = 0; nt < 4; ++nt)
            bf[nt] = *(const short8*)&Bs[(wn * 64 + nt * 16 + fr) * 32 + pk];
#pragma unroll
        for (int mt = 0; mt < 4; ++mt)
#pragma unroll
            for (int nt = 0; nt < 4; ++nt)
                acc[mt][nt] = __builtin_amdgcn_mfma_f32_16x16x32_bf16(
                    af[mt], bf[nt], acc[mt][nt], 0, 0, 0);
        __syncthreads();
    }

    // per-lane max over all 256 values (max is layout-invariant)
    float m = -3.4e38f;
#pragma unroll
    for (int mt = 0; mt < 4; ++mt)
#pragma unroll
        for (int nt = 0; nt < 4; ++nt)
#pragma unroll
            for (int i = 0; i < 4; ++i)
                m = fmaxf(m, acc[mt][nt][i]);
#pragma unroll
    for (int off = 32; off; off >>= 1)
        m = fmaxf(m, __shfl_down(m, off));
    if (lane == 0) wred[wave] = m;
    __syncthreads();
    if (tid == 0)
        blockmax[blockIdx.y * gridDim.x + blockIdx.x] =
            fmaxf(fmaxf(wred[0], wred[1]), fmaxf(wred[2], wred[3]));
}

// ---------------------------------------------------------------------------
// Kernel 3: UNNORMALIZED saliency matvecs from the bf16 copies.
// sal[0..4095]  = (A row g)  . s1     sal[4096..8191] = (B row g-HW) . s0
// one wave per row; grid 2048 x 256 (4 rows/block).
__global__ __launch_bounds__(256) void saliency_kernel(
    const short* __restrict__ Ab, const short* __restrict__ Bb,
    const float* __restrict__ s0, const float* __restrict__ s1,
    float* __restrict__ sal) {
    const int tid = threadIdx.x, lane = tid & 63, wave = tid >> 6;
    const int g = blockIdx.x * 4 + wave;          // 0..8191
    const short* x;
    const float* s;
    if (g < HW) { x = Ab + (size_t)g * CDIM;        s = s1; }
    else        { x = Bb + (size_t)(g - HW) * CDIM; s = s0; }
    float acc = 0.f;
#pragma unroll
    for (int it = 0; it < 4; ++it) {
        const int c0 = it * 512 + lane * 8;
        short8 v = *(const short8*)&x[c0];
        f32x4 sa = *(const f32x4*)&s[c0];
        f32x4 sb = *(const f32x4*)&s[c0 + 4];
#pragma unroll
        for (int j = 0; j < 4; ++j) acc += bf16s_to_f32(v[j]) * sa[j];
#pragma unroll
        for (int j = 0; j < 4; ++j) acc += bf16s_to_f32(v[4 + j]) * sb[j];
    }
#pragma unroll
    for (int off = 32; off; off >>= 1) acc += __shfl_down(acc, off);
    if (lane == 0) sal[g] = acc;
}

// ---------------------------------------------------------------------------
// Kernel 4: fused max-reduce + normalize + half-pixel bilinear 64->224.
__global__ __launch_bounds__(256) void resize_kernel(
    const float* __restrict__ sal, const float* __restrict__ bmax,
    float* __restrict__ out) {
    __shared__ float w[4];
    __shared__ float rM;
    const int tid = threadIdx.x;
    float m = -3.4e38f;
    for (int i = tid; i < 1024; i += 256) m = fmaxf(m, bmax[i]);
#pragma unroll
    for (int off = 32; off; off >>= 1) m = fmaxf(m, __shfl_down(m, off));
    if ((tid & 63) == 0) w[tid >> 6] = m;
    __syncthreads();
    if (tid == 0)
        rM = 1.0f / fmaxf(fmaxf(w[0], w[1]), fmaxf(w[2], w[3]));
    __syncthreads();

    const int idx = blockIdx.x * 256 + tid;
    if (idx >= 2 * IMG * IMG) return;
    const int ch = idx / (IMG * IMG);
    const int rem = idx % (IMG * IMG);
    const int oy = rem / IMG, ox = rem % IMG;
    const float scale = 64.0f / (float)IMG;
    const float sy = ((float)oy + 0.5f) * scale - 0.5f;
    const float sx = ((float)ox + 0.5f) * scale - 0.5f;
    const float fy0 = floorf(sy), fx0 = floorf(sx);
    const float wy = sy - fy0, wx = sx - fx0;
    int y0 = (int)fy0, x0 = (int)fx0;
    int y1 = min(max(y0 + 1, 0), 63), x1 = min(max(x0 + 1, 0), 63);
    y0 = min(max(y0, 0), 63); x0 = min(max(x0, 0), 63);
    const float* p = sal + ch * HW;
    const float v00 = p[y0 * 64 + x0], v01 = p[y0 * 64 + x1];
    const float v10 = p[y1 * 64 + x0], v11 = p[y1 * 64 + x1];
    out[idx] = ((1.f - wy) * ((1.f - wx) * v00 + wx * v01) +
                wy * ((1.f - wx) * v10 + wx * v11)) * rM;
}

// ---------------------------------------------------------------------------
extern "C" void kernel_launch(void* const* d_in, const int* in_sizes, int n_in,
                              void* d_out, int out_size, void* d_ws, size_t ws_size,
                              hipStream_t stream) {
    const float* feat = (const float*)d_in[0];   // [2,64,64,2048] fp32
    float* out = (float*)d_out;                  // [2,224,224] fp32

    // workspace layout
    char* ws = (char*)d_ws;
    short* Ab = (short*)ws;                                         // 16 MB
    short* Bb = (short*)(ws + (size_t)16 * 1024 * 1024);            // 16 MB
    float* s0   = (float*)(ws + (size_t)32 * 1024 * 1024);          // 2048
    float* s1   = s0 + CDIM;                                        // 2048
    float* bmax = s1 + CDIM;                                        // 1024
    float* sal  = bmax + 1024;                                      // 8192

    // zero the column-sum accumulators (ws is poisoned 0xAA each launch)
    hipMemsetAsync(s0, 0, 2 * CDIM * sizeof(float), stream);

    convert_colsum_kernel<<<dim3(2, 128, 2), 256, 0, stream>>>(feat, Ab, Bb, s0, s1);
    gemm_max_kernel<<<dim3(32, 32), 256, 0, stream>>>(Ab, Bb, bmax);
    saliency_kernel<<<2048, 256, 0, stream>>>(Ab, Bb, s0, s1, sal);
    const int nout = 2 * IMG * IMG;
    resize_kernel<<<(nout + 255) / 256, 256, 0, stream>>>(sal, bmax, out);
}